// Round 2
// baseline (1941.719 us; speedup 1.0000x reference)
//
#include <hip/hip_runtime.h>
#include <hip/hip_bf16.h>

// CensorNet T=512,B=256,I=128,H=256 GRU scan + BCE decode.
// R6: fused producer-consumer. One kernel, 256 blocks x 512 threads,
// 1 block/CU (90KB LDS): blocks 0..63 = serial rec scan (full 511 steps),
// blocks 64..255 = persistent gemm1 producers sweeping all 511*12 tiles.
// Producers publish per-16-step chunk counters (threadfence + release
// fetch_add, agent scope); consumers acquire-spin one chunk ahead. gi holds
// all 511 steps (no reuse) -> producers never wait -> deadlock-free.
// rec inner loop: __syncthreads replaced by lgkmcnt(0)+raw s_barrier so the
// gi prefetch stays in flight across the barrier (no vmcnt(0) drain).
// Math/bit-layout identical to R5 -> absmax 0.0 expected.

typedef __bf16 bf16x8_t __attribute__((ext_vector_type(8)));
typedef float floatx4_t __attribute__((ext_vector_type(4)));
typedef int intx4_t __attribute__((ext_vector_type(4)));
typedef unsigned int u32;
typedef u32 u32x4_t __attribute__((ext_vector_type(4)));

#define SW 2032.0f
#define SH 127.0f
#define INV_S (1.0f / (127.0f * 2032.0f))
#define NL2E (-1.44269504088896f) /* -log2(e) */
#define CRZ (NL2E * INV_S)
#define CN (2.0f * NL2E * INV_S)

#define CH_STEPS 16
#define N_CHUNK 32            /* ceil(511/16) */
#define N_PROD 192
#define N_TILE (511 * 12)

static __device__ inline u32 pack2bf(float a, float b) {
  __bf16 x = (__bf16)a, y = (__bf16)b;
  unsigned short ux = *(unsigned short*)&x, uy = *(unsigned short*)&y;
  return (u32)ux | ((u32)uy << 16);
}

// ---------------- prep: quantize W_hh/W_dec to i8, Wih->bf16, zero --------
__global__ void prep_kernel(const float* __restrict__ Whh,
                            const float* __restrict__ Wdec,
                            const float* __restrict__ Wih,
                            char* __restrict__ Wq, char* __restrict__ wdq,
                            __bf16* __restrict__ Wihb, u32* __restrict__ cnt,
                            float* __restrict__ out) {
  int idx = blockIdx.x * 256 + threadIdx.x;  // 65536 total
  for (int i = idx; i < 768 * 256; i += 65536) {
    int v = (int)rintf(Whh[i] * SW);
    v = v > 127 ? 127 : (v < -127 ? -127 : v);
    Wq[i] = (char)v;
  }
  for (int i = idx; i < 768 * 128; i += 65536) Wihb[i] = (__bf16)Wih[i];
  if (idx < 256) {
    int v = (int)rintf(Wdec[idx] * SW);
    v = v > 127 ? 127 : (v < -127 ? -127 : v);
    wdq[idx] = (char)v;
  }
  if (idx < N_CHUNK) cnt[idx] = 0;
  if (idx == 0) out[0] = 0.f;
}

// ---------------- xconv: fp32 x (steps 0..510) -> bf16 --------------------
__global__ __launch_bounds__(256) void xconv_kernel(const float* __restrict__ x,
                                                    __bf16* __restrict__ xb) {
  const size_t i = ((size_t)blockIdx.x * 256 + threadIdx.x) * 8;
  floatx4_t a = *(const floatx4_t*)(x + i);
  floatx4_t b = *(const floatx4_t*)(x + i + 4);
  bf16x8_t t;
#pragma unroll
  for (int j = 0; j < 4; ++j) {
    t[j] = (__bf16)a[j];
    t[4 + j] = (__bf16)b[j];
  }
  *(bf16x8_t*)(xb + i) = t;
}

// ---------------- fused: producers (gemm1) + consumers (rec) --------------
__global__ __launch_bounds__(512, 2) void fused_kernel(
    const char* __restrict__ Wq,   // [768][256] i8
    const char* __restrict__ wdq,  // [256] i8
    u32* __restrict__ gi,          // all 511 steps, bf16-pair units
    const float* __restrict__ gt, const float* __restrict__ bdec,
    const float* __restrict__ bhh, const float* __restrict__ bih,
    const __bf16* __restrict__ Wihb,  // [768][128] bf16
    const __bf16* __restrict__ xb,    // [511*256][128] bf16
    u32* __restrict__ cnt, float* __restrict__ out) {
  // 90112 B forces 1 block/CU (2x would exceed 160 KiB LDS).
  __shared__ __align__(16) char smem[90112];
  const int tid = threadIdx.x;

  if (blockIdx.x >= 64) {
    // ================= producer: gi = scale*(x @ Wih^T + biases) =========
    __bf16(*As)[144] = (__bf16(*)[144])smem;            // Wih tile rows n
    __bf16(*Bs)[144] = (__bf16(*)[144])(smem + 36864);  // x tile rows b
    const int j = blockIdx.x - 64;
    const int w = tid >> 6, lane = tid & 63;
    const int q = lane >> 4, nh = lane & 15;
    const int wm = w & 1, wn = w >> 1;  // 2(m) x 4(n) wave grid

    for (int tile = j; tile < N_TILE; tile += N_PROD) {
      const int t = tile / 12;
      const int s = tile - t * 12;
      const int n0 = (s >> 1) * 128;
      const int b0 = (s & 1) * 128;

      const bf16x8_t* sa = (const bf16x8_t*)(Wihb + (size_t)n0 * 128);
      const bf16x8_t* sb = (const bf16x8_t*)(xb + ((size_t)t * 256 + b0) * 128);
#pragma unroll
      for (int k = 0; k < 4; ++k) {
        const int ch = k * 512 + tid;  // 2048 bf16x8 chunks per array
        *(bf16x8_t*)&As[ch >> 4][(ch & 15) * 8] = sa[ch];
        *(bf16x8_t*)&Bs[ch >> 4][(ch & 15) * 8] = sb[ch];
      }
      __syncthreads();

      floatx4_t acc[4][2];
#pragma unroll
      for (int a = 0; a < 4; ++a)
#pragma unroll
        for (int b = 0; b < 2; ++b)
#pragma unroll
          for (int jj = 0; jj < 4; ++jj) acc[a][b][jj] = 0.f;

#pragma unroll
      for (int kk = 0; kk < 4; ++kk) {
        bf16x8_t af[4], bf[2];
#pragma unroll
        for (int mt = 0; mt < 4; ++mt)
          af[mt] = *(const bf16x8_t*)&As[wm * 64 + mt * 16 + nh][kk * 32 + q * 8];
#pragma unroll
        for (int nt = 0; nt < 2; ++nt)
          bf[nt] = *(const bf16x8_t*)&Bs[wn * 32 + nt * 16 + nh][kk * 32 + q * 8];
#pragma unroll
        for (int mt = 0; mt < 4; ++mt)
#pragma unroll
          for (int nt = 0; nt < 2; ++nt)
            acc[mt][nt] = __builtin_amdgcn_mfma_f32_16x16x32_bf16(
                af[mt], bf[nt], acc[mt][nt], 0, 0, 0);
      }

      const int gate = n0 >> 8;
      const float sc = (gate < 2) ? NL2E : (2.0f * NL2E);
      const int wr_base = ((n0 & 255) >> 5) + wm * 2;
#pragma unroll
      for (int a = 0; a < 2; ++a) {
        const int nnA = n0 + wm * 64 + a * 32 + q * 4;
        floatx4_t biasA = *(const floatx4_t*)(bih + nnA);
        floatx4_t biasB = *(const floatx4_t*)(bih + nnA + 16);
        if (gate < 2) {
          floatx4_t c1 = *(const floatx4_t*)(bhh + nnA);
          floatx4_t c2 = *(const floatx4_t*)(bhh + nnA + 16);
#pragma unroll
          for (int jj = 0; jj < 4; ++jj) {
            biasA[jj] += c1[jj];
            biasB[jj] += c2[jj];
          }
        }
        const int wrec = wr_base + a;
#pragma unroll
        for (int nt = 0; nt < 2; ++nt) {
          const int bb = b0 + wn * 32 + nt * 16 + nh;
          const int gg = (bb >> 2) & 63, jb = bb & 3;
          size_t U = (((size_t)t * 64 + gg) * 3 + gate) * 512 + wrec * 64 +
                     jb * 16 + q * 4;
          u32x4_t pv;
#pragma unroll
          for (int jj = 0; jj < 4; ++jj)
            pv[jj] = pack2bf((acc[2 * a][nt][jj] + biasA[jj]) * sc,
                             (acc[2 * a + 1][nt][jj] + biasB[jj]) * sc);
          *(u32x4_t*)(gi + U) = pv;
        }
      }
      __threadfence();  // make gi writes agent-visible
      __syncthreads();  // all writes fenced; LDS safe to reuse
      if (tid == 0)
        __hip_atomic_fetch_add(&cnt[t >> 4], 1u, __ATOMIC_RELEASE,
                               __HIP_MEMORY_SCOPE_AGENT);
    }
    return;
  }

  // ================= consumer: serial GRU scan =============================
  char(*hb)[4][288] = (char(*)[4][288])smem;  // [2][4][288] ping-pong, 2304 B
  float* logitbuf = (float*)(smem + 2304);    // 2044 floats

  const int w = tid >> 6, lane = tid & 63;
  const int q = lane >> 4, nh = lane & 15;  // q = batch row 0..3
  const int g = blockIdx.x;                 // batch slice 0..63
  const int col0 = w * 32 + nh;
  const int col1 = col0 + 16;

  intx4_t wf[6][4];
#pragma unroll
  for (int c = 0; c < 3; ++c)
#pragma unroll
    for (int ss = 0; ss < 2; ++ss) {
      const int n = c * 256 + w * 32 + ss * 16 + nh;
#pragma unroll
      for (int kb = 0; kb < 4; ++kb)
        wf[c * 2 + ss][kb] =
            *(const intx4_t*)(Wq + (size_t)n * 256 + kb * 64 + q * 16);
    }
  intx4_t wdf[4];
#pragma unroll
  for (int kb = 0; kb < 4; ++kb) {
    intx4_t z = {0, 0, 0, 0};
    intx4_t v = *(const intx4_t*)(wdq + kb * 64 + q * 16);
    wdf[kb] = (nh == 0) ? v : z;
  }

  const float bn20 = 2.0f * NL2E * bhh[512 + col0];
  const float bn21 = 2.0f * NL2E * bhh[512 + col1];
  const float bdec0 = bdec[0];

  // zero hb (h0 = 0)
  for (int i2 = tid; i2 < 576; i2 += 512) ((u32*)smem)[i2] = 0;
  float ho0 = 0.f, ho1 = 0.f;

  // wait for chunks 0 and 1 (prefetch reaches 1 step into next chunk)
  if (tid == 0) {
    while (__hip_atomic_load(&cnt[0], __ATOMIC_ACQUIRE,
                             __HIP_MEMORY_SCOPE_AGENT) < 192u)
      __builtin_amdgcn_s_sleep(1);
    while (__hip_atomic_load(&cnt[1], __ATOMIC_ACQUIRE,
                             __HIP_MEMORY_SCOPE_AGENT) < 192u)
      __builtin_amdgcn_s_sleep(1);
    __threadfence();
  }
  __syncthreads();

  u32 gcur[3], gnxt[3];
  {
    size_t u = ((size_t)g * 3) * 512 + w * 64 + lane;
#pragma unroll
    for (int c = 0; c < 3; ++c) gcur[c] = gi[u + c * 512];
  }

  int t = 0;
#pragma unroll 1
  for (int c = 0; c < N_CHUNK; ++c) {
    const int te = (c == N_CHUNK - 1) ? 511 : (c + 1) * CH_STEPS;
#pragma unroll 1
    for (; t < te; ++t) {
      const int pb = t & 1;
      {
        const int tp = (t + 1 < 511) ? t + 1 : t;
        size_t u = (((size_t)tp * 64 + g) * 3) * 512 + w * 64 + lane;
#pragma unroll
        for (int cc = 0; cc < 3; ++cc) gnxt[cc] = gi[u + cc * 512];
      }

      intx4_t hbf[4];
#pragma unroll
      for (int kb = 0; kb < 4; ++kb)
        hbf[kb] = *(const intx4_t*)&hb[pb][nh >> 2][kb * 64 + q * 16];

      intx4_t acc[6], facc;
#pragma unroll
      for (int cs = 0; cs < 6; ++cs)
#pragma unroll
        for (int jj = 0; jj < 4; ++jj) acc[cs][jj] = 0;
#pragma unroll
      for (int jj = 0; jj < 4; ++jj) facc[jj] = 0;

#pragma unroll
      for (int kb = 0; kb < 4; ++kb) {
#pragma unroll
        for (int cs = 0; cs < 6; ++cs)
          acc[cs] = __builtin_amdgcn_mfma_i32_16x16x64_i8(hbf[kb], wf[cs][kb],
                                                          acc[cs], 0, 0, 0);
        if (w == 0)
          facc = __builtin_amdgcn_mfma_i32_16x16x64_i8(hbf[kb], wdf[kb], facc,
                                                       0, 0, 0);
      }

      const float gr0 = __uint_as_float(gcur[0] << 16);
      const float gr1 = __uint_as_float(gcur[0] & 0xffff0000u);
      const float gz0 = __uint_as_float(gcur[1] << 16);
      const float gz1 = __uint_as_float(gcur[1] & 0xffff0000u);
      const float an0 = __uint_as_float(gcur[2] << 16);
      const float an1 = __uint_as_float(gcur[2] & 0xffff0000u);

      float rr0 = __builtin_amdgcn_rcpf(
          1.f + __builtin_amdgcn_exp2f((float)acc[0][0] * CRZ + gr0));
      float rr1 = __builtin_amdgcn_rcpf(
          1.f + __builtin_amdgcn_exp2f((float)acc[1][0] * CRZ + gr1));
      float zz0 = __builtin_amdgcn_rcpf(
          1.f + __builtin_amdgcn_exp2f((float)acc[2][0] * CRZ + gz0));
      float zz1 = __builtin_amdgcn_rcpf(
          1.f + __builtin_amdgcn_exp2f((float)acc[3][0] * CRZ + gz1));
      float hn20 = (float)acc[4][0] * CN + bn20;
      float hn21 = (float)acc[5][0] * CN + bn21;
      float tv0 = 2.f * __builtin_amdgcn_rcpf(
                            1.f + __builtin_amdgcn_exp2f(rr0 * hn20 + an0)) -
                  1.f;
      float tv1 = 2.f * __builtin_amdgcn_rcpf(
                            1.f + __builtin_amdgcn_exp2f(rr1 * hn21 + an1)) -
                  1.f;
      float hnew0 = tv0 + zz0 * (ho0 - tv0);
      float hnew1 = tv1 + zz1 * (ho1 - tv1);
      ho0 = hnew0;
      ho1 = hnew1;
      int h0 = (int)rintf(hnew0 * SH);
      int h1 = (int)rintf(hnew1 * SH);
      hb[1 - pb][q][col0] = (char)h0;
      hb[1 - pb][q][col1] = (char)h1;

      if (w == 0 && nh == 0 && t >= 1)
        logitbuf[(t - 1) * 4 + q] = (float)facc[0] * INV_S + bdec0;

      // light barrier: drain LDS only; gi prefetch stays in flight
      asm volatile("s_waitcnt lgkmcnt(0)" ::: "memory");
      __builtin_amdgcn_s_barrier();
      asm volatile("" ::: "memory");
#pragma unroll
      for (int cc = 0; cc < 3; ++cc) gcur[cc] = gnxt[cc];
    }
    if (c + 2 < N_CHUNK) {
      const u32 tg = (c + 2 == N_CHUNK - 1) ? 180u : 192u;
      if (tid == 0) {
        while (__hip_atomic_load(&cnt[c + 2], __ATOMIC_ACQUIRE,
                                 __HIP_MEMORY_SCOPE_AGENT) < tg)
          __builtin_amdgcn_s_sleep(1);
        __threadfence();
      }
      __syncthreads();
    }
  }

  // tail: logit of final state (t=510 wrote hb[1])
  if (w == 0) {
    intx4_t fac2 = {0, 0, 0, 0};
#pragma unroll
    for (int kb = 0; kb < 4; ++kb) {
      intx4_t b = *(const intx4_t*)&hb[1][nh >> 2][kb * 64 + q * 16];
      fac2 = __builtin_amdgcn_mfma_i32_16x16x64_i8(b, wdf[kb], fac2, 0, 0, 0);
    }
    if (nh == 0) logitbuf[510 * 4 + q] = (float)fac2[0] * INV_S + bdec0;
  }
  __syncthreads();

  // bulk BCE sweep
  float loss = 0.f;
  for (int i = tid; i < 511 * 4; i += 512) {
    float l = logitbuf[i];
    float gtv = gt[(size_t)((i >> 2) + 1) * 256 + g * 4 + (i & 3)];
    float t1 = log1pf(__expf(-fabsf(l)));
    loss += gtv * (fmaxf(-l, 0.f) + t1) + (1.f - gtv) * (fmaxf(l, 0.f) + t1);
  }
  loss += __shfl_xor(loss, 1);
  loss += __shfl_xor(loss, 2);
  loss += __shfl_xor(loss, 4);
  loss += __shfl_xor(loss, 8);
  loss += __shfl_xor(loss, 16);
  loss += __shfl_xor(loss, 32);
  if (lane == 0) atomicAdd(out, loss);
}

// ---------------- host ----------------
extern "C" void kernel_launch(void* const* d_in, const int* in_sizes, int n_in,
                              void* d_out, int out_size, void* d_ws,
                              size_t ws_size, hipStream_t stream) {
  const float* x = (const float*)d_in[0];     // [512,256,128]
  const float* gt = (const float*)d_in[1];    // [512,256,1]
  const float* Wih = (const float*)d_in[2];   // [768,128]
  const float* Whh = (const float*)d_in[3];   // [768,256]
  const float* bih = (const float*)d_in[4];   // [768]
  const float* bhh = (const float*)d_in[5];   // [768]
  const float* Wdec = (const float*)d_in[6];  // [1,256]
  const float* bdec = (const float*)d_in[7];  // [1]
  float* out = (float*)d_out;

  char* ws = (char*)d_ws;
  char* Wq = ws;                          // 196608 B
  char* wdq = ws + 196608;                // 256 B (pad 512)
  u32* cnt = (u32*)(ws + 197120);         // 128 B (pad 512)
  __bf16* Wihb = (__bf16*)(ws + 197632);  // 196608 B
  __bf16* xb = (__bf16*)(ws + 394240);    // 511*65536 = 33488896 B
  u32* gi = (u32*)(ws + 33883136);        // 511*393216 = 200933376 B
  // total 234,816,512 B <= ws budget verified by prior Tc=511 runs

  prep_kernel<<<256, 256, 0, stream>>>(Whh, Wdec, Wih, Wq, wdq, Wihb, cnt,
                                       out);
  xconv_kernel<<<8176, 256, 0, stream>>>(x, xb);
  fused_kernel<<<256, 512, 0, stream>>>(Wq, wdq, gi, gt, bdec, bhh, bih, Wihb,
                                        xb, cnt, out);
}

// Round 3
// 518.646 us; speedup vs baseline: 3.7438x; 3.7438x over previous
//
#include <hip/hip_runtime.h>
#include <hip/hip_bf16.h>

// CensorNet T=512,B=256,I=128,H=256 GRU scan + BCE decode.
// R7: R5 structure (separate prep/xconv/gemm1/rec; no cross-XCD fencing --
// R6's producer-consumer fences thrashed L2, 3.5x regression) + rec fixes:
//   (a) light per-step barrier: s_waitcnt lgkmcnt(0) + raw s_barrier only,
//       so gi prefetch loads stay in flight across the barrier (the old
//       __syncthreads drained vmcnt(0) every step, serializing ~400 cyc of
//       gi latency into the scan chain);
//   (b) depth-2 gi prefetch: manual unroll-x2 with alternating register
//       sets GA/GB; loads issued at step t are consumed at t+2 (~2 steps
//       of flight), extract-before-overwrite keeps registers SSA-clean.
// Math/bit-layout identical to R5 -> absmax 0.0 expected.

typedef __bf16 bf16x8_t __attribute__((ext_vector_type(8)));
typedef float floatx4_t __attribute__((ext_vector_type(4)));
typedef int intx4_t __attribute__((ext_vector_type(4)));
typedef unsigned int u32;
typedef u32 u32x4_t __attribute__((ext_vector_type(4)));

#define SW 2032.0f
#define SH 127.0f
#define INV_S (1.0f / (127.0f * 2032.0f))
#define NL2E (-1.44269504088896f) /* -log2(e) */
#define CRZ (NL2E * INV_S)
#define CN (2.0f * NL2E * INV_S)

static __device__ inline u32 pack2bf(float a, float b) {
  __bf16 x = (__bf16)a, y = (__bf16)b;
  unsigned short ux = *(unsigned short*)&x, uy = *(unsigned short*)&y;
  return (u32)ux | ((u32)uy << 16);
}

// ---------------- prep: quantize W_hh/W_dec to i8, Wih->bf16, zero --------
__global__ void prep_kernel(const float* __restrict__ Whh,
                            const float* __restrict__ Wdec,
                            const float* __restrict__ Wih,
                            char* __restrict__ Wq, char* __restrict__ wdq,
                            __bf16* __restrict__ Wihb,
                            float* __restrict__ h_ws, float* __restrict__ out) {
  int idx = blockIdx.x * 256 + threadIdx.x;  // 65536 total
  for (int i = idx; i < 768 * 256; i += 65536) {
    int v = (int)rintf(Whh[i] * SW);
    v = v > 127 ? 127 : (v < -127 ? -127 : v);
    Wq[i] = (char)v;
  }
  for (int i = idx; i < 768 * 128; i += 65536) Wihb[i] = (__bf16)Wih[i];
  if (idx < 256) {
    int v = (int)rintf(Wdec[idx] * SW);
    v = v > 127 ? 127 : (v < -127 ? -127 : v);
    wdq[idx] = (char)v;
  }
  if (idx < 65536) h_ws[idx] = 0.f;
  if (idx == 0) out[0] = 0.f;
}

// ---------------- xconv: fp32 x chunk -> bf16 -----------------------------
__global__ __launch_bounds__(256) void xconv_kernel(const float* __restrict__ x,
                                                    __bf16* __restrict__ xb) {
  const size_t i = ((size_t)blockIdx.x * 256 + threadIdx.x) * 8;
  floatx4_t a = *(const floatx4_t*)(x + i);
  floatx4_t b = *(const floatx4_t*)(x + i + 4);
  bf16x8_t t;
#pragma unroll
  for (int j = 0; j < 4; ++j) {
    t[j] = (__bf16)a[j];
    t[4 + j] = (__bf16)b[j];
  }
  *(bf16x8_t*)(xb + i) = t;
}

// ---------------- gemm1: gi = scale * (x @ W_ih.T + biases) ---------------
// gi layout (dword = bf16 pair for cols ss=0/ss=1, 16 apart):
//   U = (((t*64 + g)*3 + gate)*8 + wrec)*64 + jb*16 + nh_rec
// holding value for batch (g*4+jb), cols (wrec*32 + nh_rec, +16) of gate.
// Pre-scaling: r,z: NL2E*(gi+bih+bhh); n: 2*NL2E*(gi+bih).
__global__ __launch_bounds__(256) void gemm1_kernel(
    const __bf16* __restrict__ xb,    // [tc*256][128] bf16
    const __bf16* __restrict__ Wihb,  // [768][128] bf16
    const float* __restrict__ bih, const float* __restrict__ bhh,
    u32* __restrict__ giw) {
  __shared__ __bf16 As[128][144];  // Wih tile, rows n
  __shared__ __bf16 Bs[128][144];  // x tile, rows b

  const int tid = threadIdx.x;
  const int w = tid >> 6, lane = tid & 63;
  const int q = lane >> 4, nh = lane & 15;
  const int n0 = blockIdx.x * 128;
  const int b0 = blockIdx.y * 128;
  const int wm = w >> 1, wn = w & 1;

  {
    const bf16x8_t* sa = (const bf16x8_t*)(Wihb + (size_t)n0 * 128);
    const bf16x8_t* sb = (const bf16x8_t*)(xb + (size_t)b0 * 128);
    const int rr = tid >> 4, cc = (tid & 15) * 8;
#pragma unroll
    for (int v = 0; v < 8; ++v) {
      *(bf16x8_t*)&As[v * 16 + rr][cc] = sa[v * 256 + tid];
      *(bf16x8_t*)&Bs[v * 16 + rr][cc] = sb[v * 256 + tid];
    }
  }
  __syncthreads();

  floatx4_t acc[4][4];
#pragma unroll
  for (int a = 0; a < 4; ++a)
#pragma unroll
    for (int b = 0; b < 4; ++b)
#pragma unroll
      for (int j = 0; j < 4; ++j) acc[a][b][j] = 0.f;

#pragma unroll
  for (int kk = 0; kk < 4; ++kk) {
    bf16x8_t af[4], bf[4];
#pragma unroll
    for (int mt = 0; mt < 4; ++mt)
      af[mt] = *(const bf16x8_t*)&As[wm * 64 + mt * 16 + nh][kk * 32 + q * 8];
#pragma unroll
    for (int nt = 0; nt < 4; ++nt)
      bf[nt] = *(const bf16x8_t*)&Bs[wn * 64 + nt * 16 + nh][kk * 32 + q * 8];
#pragma unroll
    for (int mt = 0; mt < 4; ++mt)
#pragma unroll
      for (int nt = 0; nt < 4; ++nt)
        acc[mt][nt] = __builtin_amdgcn_mfma_f32_16x16x32_bf16(
            af[mt], bf[nt], acc[mt][nt], 0, 0, 0);
  }

  // epilogue: pack (ss=0, ss=1) = (mt even, mt odd) pairs into dwords
  const int gate = n0 >> 8;  // uniform per block (bx>>1)
  const float sc = (gate < 2) ? NL2E : (2.0f * NL2E);
  const int wr_base = ((n0 & 255) >> 5) + wm * 2;
#pragma unroll
  for (int a = 0; a < 2; ++a) {
    const int nnA = n0 + wm * 64 + a * 32 + q * 4;  // ss=0 cols (4 via j)
    floatx4_t biasA = *(const floatx4_t*)(bih + nnA);
    floatx4_t biasB = *(const floatx4_t*)(bih + nnA + 16);
    if (gate < 2) {
      floatx4_t c1 = *(const floatx4_t*)(bhh + nnA);
      floatx4_t c2 = *(const floatx4_t*)(bhh + nnA + 16);
#pragma unroll
      for (int j = 0; j < 4; ++j) {
        biasA[j] += c1[j];
        biasB[j] += c2[j];
      }
    }
    const int wrec = wr_base + a;
#pragma unroll
    for (int nt = 0; nt < 4; ++nt) {
      const int bb = b0 + wn * 64 + nt * 16 + nh;  // chunk batch row
      const int tl = bb >> 8, gg = (bb >> 2) & 63, jb = bb & 3;
      size_t U =
          (((size_t)tl * 64 + gg) * 3 + gate) * 512 + wrec * 64 + jb * 16 + q * 4;
      u32x4_t pv;
#pragma unroll
      for (int j = 0; j < 4; ++j)
        pv[j] = pack2bf((acc[2 * a][nt][j] + biasA[j]) * sc,
                        (acc[2 * a + 1][nt][j] + biasB[j]) * sc);
      *(u32x4_t*)(giw + U) = pv;
    }
  }
}

// ---------------- rec: serial scan, replicated-A i8 MFMA ------------------
__global__ __launch_bounds__(512, 2) void rec_kernel(
    const char* __restrict__ Wq,   // [768][256] i8
    const char* __restrict__ wdq,  // [256] i8
    const u32* __restrict__ gi,    // pre-scaled bf16-pair units
    const float* __restrict__ gt, const float* __restrict__ bdec,
    const float* __restrict__ bhh, float* __restrict__ h_ws,
    float* __restrict__ out, int t0, int tc) {
  __shared__ char hb[2][4][288];   // h i8 ping-pong; stride 288 (2-way free)
  __shared__ float logitbuf[2048]; // per-step logits, BCE'd post-loop

  const int tid = threadIdx.x;
  const int w = tid >> 6, lane = tid & 63;
  const int q = lane >> 4, nh = lane & 15;  // q = batch row 0..3
  const int g = blockIdx.x;                 // batch slice 0..63 (4 rows)
  const int col0 = w * 32 + nh;             // this lane's two h cols
  const int col1 = col0 + 16;

  // W_hh fragments (i8, B-operand):
  // wf[c*2+ss][kb] holds Whh_q[n = c*256 + w*32 + ss*16 + nh][kb*64+q*16+..]
  intx4_t wf[6][4];
#pragma unroll
  for (int c = 0; c < 3; ++c)
#pragma unroll
    for (int ss = 0; ss < 2; ++ss) {
      const int n = c * 256 + w * 32 + ss * 16 + nh;
#pragma unroll
      for (int kb = 0; kb < 4; ++kb)
        wf[c * 2 + ss][kb] =
            *(const intx4_t*)(Wq + (size_t)n * 256 + kb * 64 + q * 16);
    }
  intx4_t wdf[4];  // Wdec as B-operand: col 0 = Wdec, others zero
#pragma unroll
  for (int kb = 0; kb < 4; ++kb) {
    intx4_t z = {0, 0, 0, 0};
    intx4_t v = *(const intx4_t*)(wdq + kb * 64 + q * 16);
    wdf[kb] = (nh == 0) ? v : z;
  }

  const float bn20 = 2.0f * NL2E * bhh[512 + col0];
  const float bn21 = 2.0f * NL2E * bhh[512 + col1];
  const float bdec0 = bdec[0];

  // stage initial h rows 0..3 quantized (256 words)
  if (tid < 256) {
    const int rr = tid >> 6, c0 = (tid & 63) * 4;
    u32 p = 0;
#pragma unroll
    for (int j = 0; j < 4; ++j) {
      int a = (int)rintf(h_ws[(size_t)(g * 4 + rr) * 256 + c0 + j] * SH);
      a = a > 127 ? 127 : (a < -127 ? -127 : a);
      p |= ((u32)(a & 255)) << (8 * j);
    }
    *(u32*)&hb[0][rr][c0] = p;
  }
  float ho0 = h_ws[(size_t)(g * 4 + q) * 256 + col0];
  float ho1 = h_ws[(size_t)(g * 4 + q) * 256 + col1];
  __syncthreads();

  const int tcm1 = tc - 1;
  // depth-2 prefetch register sets
  u32 GA[3], GB[3];
  {
    size_t u0 = ((size_t)g * 3) * 512 + w * 64 + lane;
#pragma unroll
    for (int c = 0; c < 3; ++c) GA[c] = gi[u0 + c * 512];
    const int t1 = tc > 1 ? 1 : 0;
    size_t u1 = (((size_t)t1 * 64 + g) * 3) * 512 + w * 64 + lane;
#pragma unroll
    for (int c = 0; c < 3; ++c) GB[c] = gi[u1 + c * 512];
  }

  // one GRU step: consumes G (gi of step T), then refills G from step TPRE
  auto STEP = [&](int T, u32* G, int TPRE) {
    const int pb = T & 1;
    intx4_t hbf[4];
#pragma unroll
    for (int kb = 0; kb < 4; ++kb)
      hbf[kb] = *(const intx4_t*)&hb[pb][nh >> 2][kb * 64 + q * 16];

    // extract old G (vmcnt wait lands here, ~2 steps after issue), then
    // refill G for step T+2 (stays in flight across 2 light barriers)
    const float gr0 = __uint_as_float(G[0] << 16);
    const float gr1 = __uint_as_float(G[0] & 0xffff0000u);
    const float gz0 = __uint_as_float(G[1] << 16);
    const float gz1 = __uint_as_float(G[1] & 0xffff0000u);
    const float an0 = __uint_as_float(G[2] << 16);
    const float an1 = __uint_as_float(G[2] & 0xffff0000u);
    {
      size_t up = (((size_t)TPRE * 64 + g) * 3) * 512 + w * 64 + lane;
#pragma unroll
      for (int c = 0; c < 3; ++c) G[c] = gi[up + c * 512];
    }

    intx4_t acc[6], facc;
#pragma unroll
    for (int cs = 0; cs < 6; ++cs)
#pragma unroll
      for (int jj = 0; jj < 4; ++jj) acc[cs][jj] = 0;
#pragma unroll
    for (int jj = 0; jj < 4; ++jj) facc[jj] = 0;

#pragma unroll
    for (int kb = 0; kb < 4; ++kb) {
#pragma unroll
      for (int cs = 0; cs < 6; ++cs)
        acc[cs] = __builtin_amdgcn_mfma_i32_16x16x64_i8(hbf[kb], wf[cs][kb],
                                                        acc[cs], 0, 0, 0);
      if (w == 0)
        facc = __builtin_amdgcn_mfma_i32_16x16x64_i8(hbf[kb], wdf[kb], facc,
                                                     0, 0, 0);
    }
    // acc[cs][0] = gh[batch q][col w*32 + (cs&1)*16 + nh] -- in-register.

    float rr0 = __builtin_amdgcn_rcpf(
        1.f + __builtin_amdgcn_exp2f((float)acc[0][0] * CRZ + gr0));
    float rr1 = __builtin_amdgcn_rcpf(
        1.f + __builtin_amdgcn_exp2f((float)acc[1][0] * CRZ + gr1));
    float zz0 = __builtin_amdgcn_rcpf(
        1.f + __builtin_amdgcn_exp2f((float)acc[2][0] * CRZ + gz0));
    float zz1 = __builtin_amdgcn_rcpf(
        1.f + __builtin_amdgcn_exp2f((float)acc[3][0] * CRZ + gz1));
    float hn20 = (float)acc[4][0] * CN + bn20;
    float hn21 = (float)acc[5][0] * CN + bn21;
    float tv0 = 2.f * __builtin_amdgcn_rcpf(
                          1.f + __builtin_amdgcn_exp2f(rr0 * hn20 + an0)) -
                1.f;
    float tv1 = 2.f * __builtin_amdgcn_rcpf(
                          1.f + __builtin_amdgcn_exp2f(rr1 * hn21 + an1)) -
                1.f;
    float hnew0 = tv0 + zz0 * (ho0 - tv0);
    float hnew1 = tv1 + zz1 * (ho1 - tv1);
    ho0 = hnew0;
    ho1 = hnew1;
    int h0 = (int)rintf(hnew0 * SH);
    int h1 = (int)rintf(hnew1 * SH);
    hb[1 - pb][q][col0] = (char)h0;
    hb[1 - pb][q][col1] = (char)h1;

    if (w == 0 && nh == 0 && T >= 1)  // facc[0] = logit-pre of batch q
      logitbuf[(T - 1) * 4 + q] = (float)facc[0] * INV_S + bdec0;

    // light barrier: drain LDS only; gi prefetch stays in flight
    asm volatile("s_waitcnt lgkmcnt(0)" ::: "memory");
    __builtin_amdgcn_s_barrier();
    asm volatile("" ::: "memory");
  };

  int t = 0;
#pragma unroll 1
  for (; t + 1 < tc; t += 2) {
    STEP(t, GA, (t + 2 <= tcm1) ? t + 2 : tcm1);
    STEP(t + 1, GB, (t + 3 <= tcm1) ? t + 3 : tcm1);
  }
  if (t < tc) STEP(t, GA, tcm1);

  // tail: logit of final state
  if (w == 0) {
    intx4_t fac2 = {0, 0, 0, 0};
#pragma unroll
    for (int kb = 0; kb < 4; ++kb) {
      intx4_t b = *(const intx4_t*)&hb[tc & 1][nh >> 2][kb * 64 + q * 16];
      fac2 = __builtin_amdgcn_mfma_i32_16x16x64_i8(b, wdf[kb], fac2, 0, 0, 0);
    }
    if (nh == 0) logitbuf[(tc - 1) * 4 + q] = (float)fac2[0] * INV_S + bdec0;
  }
  __syncthreads();

  // bulk BCE sweep
  float loss = 0.f;
  for (int i = tid; i < tc * 4; i += 512) {
    float l = logitbuf[i];
    float gtv = gt[(size_t)(t0 + (i >> 2) + 1) * 256 + g * 4 + (i & 3)];
    float t1 = log1pf(__expf(-fabsf(l)));
    loss += gtv * (fmaxf(-l, 0.f) + t1) + (1.f - gtv) * (fmaxf(l, 0.f) + t1);
  }
  loss += __shfl_xor(loss, 1);
  loss += __shfl_xor(loss, 2);
  loss += __shfl_xor(loss, 4);
  loss += __shfl_xor(loss, 8);
  loss += __shfl_xor(loss, 16);
  loss += __shfl_xor(loss, 32);
  if (lane == 0) atomicAdd(out, loss);

  // persist h (fp32) for next chunk
  h_ws[(size_t)(g * 4 + q) * 256 + col0] = ho0;
  h_ws[(size_t)(g * 4 + q) * 256 + col1] = ho1;
}

// ---------------- host ----------------
extern "C" void kernel_launch(void* const* d_in, const int* in_sizes, int n_in,
                              void* d_out, int out_size, void* d_ws,
                              size_t ws_size, hipStream_t stream) {
  const float* x = (const float*)d_in[0];     // [512,256,128]
  const float* gt = (const float*)d_in[1];    // [512,256,1]
  const float* Wih = (const float*)d_in[2];   // [768,128]
  const float* Whh = (const float*)d_in[3];   // [768,256]
  const float* bih = (const float*)d_in[4];   // [768]
  const float* bhh = (const float*)d_in[5];   // [768]
  const float* Wdec = (const float*)d_in[6];  // [1,256]
  const float* bdec = (const float*)d_in[7];  // [1]
  float* out = (float*)d_out;

  char* ws = (char*)d_ws;
  char* Wq = ws;                          // 196608 B
  char* wdq = ws + 196608;                // 512 B (256 used)
  float* h_ws = (float*)(ws + 197120);    // 262144 B
  __bf16* Wihb = (__bf16*)(ws + 459264);  // 196608 B
  char* dyn = ws + 655872;
  const size_t per_step = (size_t)393216 + 65536;  // gi + xb per time step
  size_t avail = ws_size > 655872 ? ws_size - 655872 : per_step;
  int Tc = (int)(avail / per_step);
  if (Tc < 1) Tc = 1;
  if (Tc > 511) Tc = 511;
  __bf16* xb = (__bf16*)dyn;                        // Tc*65536 B
  u32* gi = (u32*)(dyn + (size_t)Tc * 65536);       // Tc*393216 B

  prep_kernel<<<256, 256, 0, stream>>>(Whh, Wdec, Wih, Wq, wdq, Wihb, h_ws,
                                       out);
  for (int t0 = 0; t0 < 511; t0 += Tc) {
    const int tc = (511 - t0 < Tc) ? (511 - t0) : Tc;
    xconv_kernel<<<tc * 16, 256, 0, stream>>>(x + (size_t)t0 * 256 * 128, xb);
    gemm1_kernel<<<dim3(6, tc * 2), 256, 0, stream>>>(xb, Wihb, bih, bhh, gi);
    rec_kernel<<<64, 512, 0, stream>>>(Wq, wdq, gi, gt, bdec, bhh, h_ws, out,
                                       t0, tc);
  }
}

// Round 4
// 517.996 us; speedup vs baseline: 3.7485x; 1.0013x over previous
//
#include <hip/hip_runtime.h>
#include <hip/hip_bf16.h>

// CensorNet T=512,B=256,I=128,H=256 GRU scan + BCE decode.
// R8: 16-wave rec (1024 thr/block). Each wave owns 16 h-cols x 3 gates
// (3 chains x 4 kb = 12 MFMA/wave, 1 gate elem/lane). Same 192 MFMA/CU/step
// (matrix floor ~980 cyc) but 4 waves/SIMD overlap VALU tails with MFMA
// issue and halve per-wave chain length. Decoder MFMA split into 4
// independent 1-kb partials on waves 12..15 (one per SIMD -> 49 MFMA/SIMD
// balanced; partial ints < 2^24 stored as fp32, summed exactly at BCE).
// gi layout unchanged: wave pair (2k,2k+1) reads same dword, selects
// lo/hi half (wave-uniform). Light barrier + depth-2 gi prefetch kept.
// Bit-identical math -> absmax 0.0 expected.

typedef __bf16 bf16x8_t __attribute__((ext_vector_type(8)));
typedef float floatx4_t __attribute__((ext_vector_type(4)));
typedef int intx4_t __attribute__((ext_vector_type(4)));
typedef unsigned int u32;
typedef u32 u32x4_t __attribute__((ext_vector_type(4)));

#define SW 2032.0f
#define SH 127.0f
#define INV_S (1.0f / (127.0f * 2032.0f))
#define NL2E (-1.44269504088896f) /* -log2(e) */
#define CRZ (NL2E * INV_S)
#define CN (2.0f * NL2E * INV_S)

static __device__ inline u32 pack2bf(float a, float b) {
  __bf16 x = (__bf16)a, y = (__bf16)b;
  unsigned short ux = *(unsigned short*)&x, uy = *(unsigned short*)&y;
  return (u32)ux | ((u32)uy << 16);
}

// ---------------- prep: quantize W_hh/W_dec to i8, Wih->bf16, zero --------
__global__ void prep_kernel(const float* __restrict__ Whh,
                            const float* __restrict__ Wdec,
                            const float* __restrict__ Wih,
                            char* __restrict__ Wq, char* __restrict__ wdq,
                            __bf16* __restrict__ Wihb,
                            float* __restrict__ h_ws, float* __restrict__ out) {
  int idx = blockIdx.x * 256 + threadIdx.x;  // 65536 total
  for (int i = idx; i < 768 * 256; i += 65536) {
    int v = (int)rintf(Whh[i] * SW);
    v = v > 127 ? 127 : (v < -127 ? -127 : v);
    Wq[i] = (char)v;
  }
  for (int i = idx; i < 768 * 128; i += 65536) Wihb[i] = (__bf16)Wih[i];
  if (idx < 256) {
    int v = (int)rintf(Wdec[idx] * SW);
    v = v > 127 ? 127 : (v < -127 ? -127 : v);
    wdq[idx] = (char)v;
  }
  if (idx < 65536) h_ws[idx] = 0.f;
  if (idx == 0) out[0] = 0.f;
}

// ---------------- xconv: fp32 x chunk -> bf16 -----------------------------
__global__ __launch_bounds__(256) void xconv_kernel(const float* __restrict__ x,
                                                    __bf16* __restrict__ xb) {
  const size_t i = ((size_t)blockIdx.x * 256 + threadIdx.x) * 8;
  floatx4_t a = *(const floatx4_t*)(x + i);
  floatx4_t b = *(const floatx4_t*)(x + i + 4);
  bf16x8_t t;
#pragma unroll
  for (int j = 0; j < 4; ++j) {
    t[j] = (__bf16)a[j];
    t[4 + j] = (__bf16)b[j];
  }
  *(bf16x8_t*)(xb + i) = t;
}

// ---------------- gemm1: gi = scale * (x @ W_ih.T + biases) ---------------
// gi layout (dword = bf16 pair for cols ss=0/ss=1, 16 apart):
//   U = (((t*64 + g)*3 + gate)*8 + wrec)*64 + jb*16 + nh_rec
// holding value for batch (g*4+jb), cols (wrec*32 + nh_rec, +16) of gate.
// Pre-scaling: r,z: NL2E*(gi+bih+bhh); n: 2*NL2E*(gi+bih).
__global__ __launch_bounds__(256) void gemm1_kernel(
    const __bf16* __restrict__ xb,    // [tc*256][128] bf16
    const __bf16* __restrict__ Wihb,  // [768][128] bf16
    const float* __restrict__ bih, const float* __restrict__ bhh,
    u32* __restrict__ giw) {
  __shared__ __bf16 As[128][144];  // Wih tile, rows n
  __shared__ __bf16 Bs[128][144];  // x tile, rows b

  const int tid = threadIdx.x;
  const int w = tid >> 6, lane = tid & 63;
  const int q = lane >> 4, nh = lane & 15;
  const int n0 = blockIdx.x * 128;
  const int b0 = blockIdx.y * 128;
  const int wm = w >> 1, wn = w & 1;

  {
    const bf16x8_t* sa = (const bf16x8_t*)(Wihb + (size_t)n0 * 128);
    const bf16x8_t* sb = (const bf16x8_t*)(xb + (size_t)b0 * 128);
    const int rr = tid >> 4, cc = (tid & 15) * 8;
#pragma unroll
    for (int v = 0; v < 8; ++v) {
      *(bf16x8_t*)&As[v * 16 + rr][cc] = sa[v * 256 + tid];
      *(bf16x8_t*)&Bs[v * 16 + rr][cc] = sb[v * 256 + tid];
    }
  }
  __syncthreads();

  floatx4_t acc[4][4];
#pragma unroll
  for (int a = 0; a < 4; ++a)
#pragma unroll
    for (int b = 0; b < 4; ++b)
#pragma unroll
      for (int j = 0; j < 4; ++j) acc[a][b][j] = 0.f;

#pragma unroll
  for (int kk = 0; kk < 4; ++kk) {
    bf16x8_t af[4], bf[4];
#pragma unroll
    for (int mt = 0; mt < 4; ++mt)
      af[mt] = *(const bf16x8_t*)&As[wm * 64 + mt * 16 + nh][kk * 32 + q * 8];
#pragma unroll
    for (int nt = 0; nt < 4; ++nt)
      bf[nt] = *(const bf16x8_t*)&Bs[wn * 64 + nt * 16 + nh][kk * 32 + q * 8];
#pragma unroll
    for (int mt = 0; mt < 4; ++mt)
#pragma unroll
      for (int nt = 0; nt < 4; ++nt)
        acc[mt][nt] = __builtin_amdgcn_mfma_f32_16x16x32_bf16(
            af[mt], bf[nt], acc[mt][nt], 0, 0, 0);
  }

  // epilogue: pack (ss=0, ss=1) = (mt even, mt odd) pairs into dwords
  const int gate = n0 >> 8;  // uniform per block (bx>>1)
  const float sc = (gate < 2) ? NL2E : (2.0f * NL2E);
  const int wr_base = ((n0 & 255) >> 5) + wm * 2;
#pragma unroll
  for (int a = 0; a < 2; ++a) {
    const int nnA = n0 + wm * 64 + a * 32 + q * 4;  // ss=0 cols (4 via j)
    floatx4_t biasA = *(const floatx4_t*)(bih + nnA);
    floatx4_t biasB = *(const floatx4_t*)(bih + nnA + 16);
    if (gate < 2) {
      floatx4_t c1 = *(const floatx4_t*)(bhh + nnA);
      floatx4_t c2 = *(const floatx4_t*)(bhh + nnA + 16);
#pragma unroll
      for (int j = 0; j < 4; ++j) {
        biasA[j] += c1[j];
        biasB[j] += c2[j];
      }
    }
    const int wrec = wr_base + a;
#pragma unroll
    for (int nt = 0; nt < 4; ++nt) {
      const int bb = b0 + wn * 64 + nt * 16 + nh;  // chunk batch row
      const int tl = bb >> 8, gg = (bb >> 2) & 63, jb = bb & 3;
      size_t U =
          (((size_t)tl * 64 + gg) * 3 + gate) * 512 + wrec * 64 + jb * 16 + q * 4;
      u32x4_t pv;
#pragma unroll
      for (int j = 0; j < 4; ++j)
        pv[j] = pack2bf((acc[2 * a][nt][j] + biasA[j]) * sc,
                        (acc[2 * a + 1][nt][j] + biasB[j]) * sc);
      *(u32x4_t*)(giw + U) = pv;
    }
  }
}

// ---------------- rec: serial scan, 16 waves, replicated-A i8 MFMA --------
__global__ __launch_bounds__(1024) void rec_kernel(
    const char* __restrict__ Wq,   // [768][256] i8
    const char* __restrict__ wdq,  // [256] i8
    const u32* __restrict__ gi,    // pre-scaled bf16-pair units
    const float* __restrict__ gt, const float* __restrict__ bdec,
    const float* __restrict__ bhh, float* __restrict__ h_ws,
    float* __restrict__ out, int t0, int tc) {
  __shared__ char hb[2][4][288];  // h i8 ping-pong; stride 288 (2-way free)
  __shared__ float lp[4][2048];   // decoder partials (kb 0..3), exact ints

  const int tid = threadIdx.x;
  const int w = tid >> 6, lane = tid & 63;  // wave 0..15
  const int q = lane >> 4, nh = lane & 15;  // q = batch row 0..3
  const int g = blockIdx.x;                 // batch slice 0..63 (4 rows)
  const int col = w * 16 + nh;              // this lane's single h col
  const int wp = w >> 1;                    // gi dword group
  const int hi = w & 1;                     // lo/hi bf16 half (wave-uniform)

  // W_hh fragments (i8, B-operand): wave owns cols w*16..+15 for 3 gates
  intx4_t wf[3][4];
#pragma unroll
  for (int c = 0; c < 3; ++c) {
    const int n = c * 256 + col;
#pragma unroll
    for (int kb = 0; kb < 4; ++kb)
      wf[c][kb] = *(const intx4_t*)(Wq + (size_t)n * 256 + kb * 64 + q * 16);
  }
  // Wdec fragment: wave 12+kb owns k-block kb (others: dummy kb=0, unused)
  intx4_t wdfk;
  {
    const int kb = (w >= 12) ? (w - 12) : 0;
    intx4_t z = {0, 0, 0, 0};
    intx4_t v = *(const intx4_t*)(wdq + kb * 64 + q * 16);
    wdfk = (nh == 0) ? v : z;  // B col 0 = Wdec
  }

  const float bn2 = 2.0f * NL2E * bhh[512 + col];
  const float bdec0 = bdec[0];

  // stage initial h rows 0..3 quantized (256 words)
  if (tid < 256) {
    const int rr = tid >> 6, c0 = (tid & 63) * 4;
    u32 p = 0;
#pragma unroll
    for (int j = 0; j < 4; ++j) {
      int a = (int)rintf(h_ws[(size_t)(g * 4 + rr) * 256 + c0 + j] * SH);
      a = a > 127 ? 127 : (a < -127 ? -127 : a);
      p |= ((u32)(a & 255)) << (8 * j);
    }
    *(u32*)&hb[0][rr][c0] = p;
  }
  float ho = h_ws[(size_t)(g * 4 + q) * 256 + col];
  __syncthreads();

  const int tcm1 = tc - 1;
  const size_t boff = (size_t)wp * 64 + q * 16 + nh;
  // depth-2 prefetch register sets
  u32 GA[3], GB[3];
  {
    size_t u0 = ((size_t)g * 3) * 512 + boff;
#pragma unroll
    for (int c = 0; c < 3; ++c) GA[c] = gi[u0 + c * 512];
    const int t1s = tc > 1 ? 1 : 0;
    size_t u1 = (((size_t)t1s * 64 + g) * 3) * 512 + boff;
#pragma unroll
    for (int c = 0; c < 3; ++c) GB[c] = gi[u1 + c * 512];
  }

  // one GRU step: consumes G (gi of step T), then refills G from step TPRE
  auto STEP = [&](int T, u32* G, int TPRE) {
    const int pb = T & 1;
    intx4_t hbf[4];  // A-operand: row m holds h[m>>2] (4-lane broadcast)
#pragma unroll
    for (int kb = 0; kb < 4; ++kb)
      hbf[kb] = *(const intx4_t*)&hb[pb][nh >> 2][kb * 64 + q * 16];

    // extract old G (issued ~2 steps ago), then refill for step T+2
    float gv0, gv1, gv2;
    if (hi) {
      gv0 = __uint_as_float(G[0] & 0xffff0000u);
      gv1 = __uint_as_float(G[1] & 0xffff0000u);
      gv2 = __uint_as_float(G[2] & 0xffff0000u);
    } else {
      gv0 = __uint_as_float(G[0] << 16);
      gv1 = __uint_as_float(G[1] << 16);
      gv2 = __uint_as_float(G[2] << 16);
    }
    {
      size_t up = (((size_t)TPRE * 64 + g) * 3) * 512 + boff;
#pragma unroll
      for (int c = 0; c < 3; ++c) G[c] = gi[up + c * 512];
    }

    intx4_t acc[3];
#pragma unroll
    for (int cs = 0; cs < 3; ++cs)
#pragma unroll
      for (int jj = 0; jj < 4; ++jj) acc[cs][jj] = 0;

#pragma unroll
    for (int kb = 0; kb < 4; ++kb)
#pragma unroll
      for (int cs = 0; cs < 3; ++cs)
        acc[cs] = __builtin_amdgcn_mfma_i32_16x16x64_i8(hbf[kb], wf[cs][kb],
                                                        acc[cs], 0, 0, 0);
    // acc[cs][0] = gh[batch q][col] for gate cs -- in-register.

    // decoder partial: waves 12..15, one k-block each (one per SIMD)
    if (w >= 12) {
      intx4_t hsel = (w == 12) ? hbf[0]
                   : (w == 13) ? hbf[1]
                   : (w == 14) ? hbf[2] : hbf[3];
      intx4_t facc = {0, 0, 0, 0};
      facc = __builtin_amdgcn_mfma_i32_16x16x64_i8(hsel, wdfk, facc, 0, 0, 0);
      if (nh == 0 && T >= 1) lp[w - 12][(T - 1) * 4 + q] = (float)facc[0];
    }

    float rr0 = __builtin_amdgcn_rcpf(
        1.f + __builtin_amdgcn_exp2f((float)acc[0][0] * CRZ + gv0));
    float zz0 = __builtin_amdgcn_rcpf(
        1.f + __builtin_amdgcn_exp2f((float)acc[1][0] * CRZ + gv1));
    float hn2 = (float)acc[2][0] * CN + bn2;
    float tv0 = 2.f * __builtin_amdgcn_rcpf(
                          1.f + __builtin_amdgcn_exp2f(rr0 * hn2 + gv2)) -
                1.f;
    float hnew = tv0 + zz0 * (ho - tv0);
    ho = hnew;
    int h8 = (int)rintf(hnew * SH);
    hb[1 - pb][q][col] = (char)h8;

    // light barrier: drain LDS only; gi prefetch stays in flight
    asm volatile("s_waitcnt lgkmcnt(0)" ::: "memory");
    __builtin_amdgcn_s_barrier();
    asm volatile("" ::: "memory");
  };

  int t = 0;
#pragma unroll 1
  for (; t + 1 < tc; t += 2) {
    STEP(t, GA, (t + 2 <= tcm1) ? t + 2 : tcm1);
    STEP(t + 1, GB, (t + 3 <= tcm1) ? t + 3 : tcm1);
  }
  if (t < tc) STEP(t, GA, tcm1);

  // tail: decoder partials of final state
  if (w >= 12) {
    const int kb = w - 12;
    intx4_t b = *(const intx4_t*)&hb[tc & 1][nh >> 2][kb * 64 + q * 16];
    intx4_t fac2 = {0, 0, 0, 0};
    fac2 = __builtin_amdgcn_mfma_i32_16x16x64_i8(b, wdfk, fac2, 0, 0, 0);
    if (nh == 0) lp[kb][(tc - 1) * 4 + q] = (float)fac2[0];
  }
  __syncthreads();

  // bulk BCE sweep (partial sums are exact: each < 2^20, sum < 2^23)
  float loss = 0.f;
  for (int i = tid; i < tc * 4; i += 1024) {
    float l = (lp[0][i] + lp[1][i] + lp[2][i] + lp[3][i]) * INV_S + bdec0;
    float gtv = gt[(size_t)(t0 + (i >> 2) + 1) * 256 + g * 4 + (i & 3)];
    float t1 = log1pf(__expf(-fabsf(l)));
    loss += gtv * (fmaxf(-l, 0.f) + t1) + (1.f - gtv) * (fmaxf(l, 0.f) + t1);
  }
  loss += __shfl_xor(loss, 1);
  loss += __shfl_xor(loss, 2);
  loss += __shfl_xor(loss, 4);
  loss += __shfl_xor(loss, 8);
  loss += __shfl_xor(loss, 16);
  loss += __shfl_xor(loss, 32);
  if (lane == 0) atomicAdd(out, loss);

  // persist h (fp32) for next chunk
  h_ws[(size_t)(g * 4 + q) * 256 + col] = ho;
}

// ---------------- host ----------------
extern "C" void kernel_launch(void* const* d_in, const int* in_sizes, int n_in,
                              void* d_out, int out_size, void* d_ws,
                              size_t ws_size, hipStream_t stream) {
  const float* x = (const float*)d_in[0];     // [512,256,128]
  const float* gt = (const float*)d_in[1];    // [512,256,1]
  const float* Wih = (const float*)d_in[2];   // [768,128]
  const float* Whh = (const float*)d_in[3];   // [768,256]
  const float* bih = (const float*)d_in[4];   // [768]
  const float* bhh = (const float*)d_in[5];   // [768]
  const float* Wdec = (const float*)d_in[6];  // [1,256]
  const float* bdec = (const float*)d_in[7];  // [1]
  float* out = (float*)d_out;

  char* ws = (char*)d_ws;
  char* Wq = ws;                          // 196608 B
  char* wdq = ws + 196608;                // 512 B (256 used)
  float* h_ws = (float*)(ws + 197120);    // 262144 B
  __bf16* Wihb = (__bf16*)(ws + 459264);  // 196608 B
  char* dyn = ws + 655872;
  const size_t per_step = (size_t)393216 + 65536;  // gi + xb per time step
  size_t avail = ws_size > 655872 ? ws_size - 655872 : per_step;
  int Tc = (int)(avail / per_step);
  if (Tc < 1) Tc = 1;
  if (Tc > 511) Tc = 511;
  __bf16* xb = (__bf16*)dyn;                        // Tc*65536 B
  u32* gi = (u32*)(dyn + (size_t)Tc * 65536);       // Tc*393216 B

  prep_kernel<<<256, 256, 0, stream>>>(Whh, Wdec, Wih, Wq, wdq, Wihb, h_ws,
                                       out);
  for (int t0 = 0; t0 < 511; t0 += Tc) {
    const int tc = (511 - t0 < Tc) ? (511 - t0) : Tc;
    xconv_kernel<<<tc * 16, 256, 0, stream>>>(x + (size_t)t0 * 256 * 128, xb);
    gemm1_kernel<<<dim3(6, tc * 2), 256, 0, stream>>>(xb, Wihb, bih, bhh, gi);
    rec_kernel<<<64, 1024, 0, stream>>>(Wq, wdq, gi, gt, bdec, bhh, h_ws, out,
                                        t0, tc);
  }
}